// Round 1
// baseline (104.557 us; speedup 1.0000x reference)
//
#include <hip/hip_runtime.h>
#include <math.h>

#define IN_TOL_F 1e-5f
#define DEN_EPS_F 1e-10f

__device__ __forceinline__ float pseudo_angle(float dx, float dy) {
    // Strictly monotone surrogate for atan2(dy, dx) over (-pi, pi]:
    // maps to [-2, 2], same sort order. atan2(0,0)=0 -> returns 0.
    float denom = fabsf(dx) + fabsf(dy);
    float p = (denom > 0.0f) ? (1.0f - __fdividef(dx, denom)) : 0.0f;
    return copysignf(p, dy);
}

__global__ __launch_bounds__(256) void riou_loss_kernel(
        const float* __restrict__ pred, const float* __restrict__ target,
        float* __restrict__ out, int n, float inv_n) {
    int i = blockIdx.x * blockDim.x + threadIdx.x;
    float loss = 0.0f;
    if (i < n) {
        const float* pb = pred + (size_t)i * 5;
        const float* tb = target + (size_t)i * 5;
        float x1 = pb[0], y1 = pb[1], w1 = pb[2], h1 = pb[3], a1 = pb[4];
        float x2 = tb[0], y2 = tb[1], w2 = tb[2], h2 = tb[3], a2 = tb[4];
        float s1, c1, s2, c2;
        sincosf(a1, &s1, &c1);
        sincosf(a2, &s2, &c2);

        // corners: dx factors [-1,1,1,-1]*w/2, dy factors [-1,-1,1,1]*h/2
        const float KX[4] = {-0.5f, 0.5f, 0.5f, -0.5f};
        const float KY[4] = {-0.5f, -0.5f, 0.5f, 0.5f};
        float px[4], py[4], qx[4], qy[4];
#pragma unroll
        for (int k = 0; k < 4; ++k) {
            float dx = KX[k] * w1, dy = KY[k] * h1;
            px[k] = x1 + dx * c1 - dy * s1;
            py[k] = y1 + dx * s1 + dy * c1;
            float ex = KX[k] * w2, ey = KY[k] * h2;
            qx[k] = x2 + ex * c2 - ey * s2;
            qy[k] = y2 + ex * s2 + ey * c2;
        }
        float rxv[4], ryv[4], sxv[4], syv[4];
#pragma unroll
        for (int k = 0; k < 4; ++k) {
            rxv[k] = px[(k + 1) & 3] - px[k];
            ryv[k] = py[(k + 1) & 3] - py[k];
            sxv[k] = qx[(k + 1) & 3] - qx[k];
            syv[k] = qy[(k + 1) & 3] - qy[k];
        }

        float ptx[24], pty[24], ang[24];
        bool msk[24];

        // 16 edge-edge intersections (pred edge k, target edge l)
#pragma unroll
        for (int k = 0; k < 4; ++k) {
#pragma unroll
            for (int l = 0; l < 4; ++l) {
                int idx = k * 4 + l;
                float qpx = qx[l] - px[k], qpy = qy[l] - py[k];
                float den = rxv[k] * syv[l] - ryv[k] * sxv[l];
                bool den_ok = fabsf(den) > DEN_EPS_F;
                float den_safe = den_ok ? den : 1.0f;
                float invd = 1.0f / den_safe;
                float t = (qpx * syv[l] - qpy * sxv[l]) * invd;
                float u = (qpx * ryv[k] - qpy * rxv[k]) * invd;
                bool ok = den_ok & (t >= 0.0f) & (t <= 1.0f) & (u >= 0.0f) & (u <= 1.0f);
                float ts = ok ? t : 0.0f;
                ptx[idx] = px[k] + ts * rxv[k];
                pty[idx] = py[k] + ts * ryv[k];
                msk[idx] = ok;
            }
        }

        // corner containment tests
        float hw2 = w2 * 0.5f + IN_TOL_F, hh2 = h2 * 0.5f + IN_TOL_F;
        float hw1 = w1 * 0.5f + IN_TOL_F, hh1 = h1 * 0.5f + IN_TOL_F;
#pragma unroll
        for (int k = 0; k < 4; ++k) {
            ptx[16 + k] = px[k];
            pty[16 + k] = py[k];
            float dx = px[k] - x2, dy = py[k] - y2;
            float lx = dx * c2 + dy * s2;
            float ly = -dx * s2 + dy * c2;
            msk[16 + k] = (fabsf(lx) <= hw2) & (fabsf(ly) <= hh2);

            ptx[20 + k] = qx[k];
            pty[20 + k] = qy[k];
            float dX = qx[k] - x1, dY = qy[k] - y1;
            float lX = dX * c1 + dY * s1;
            float lY = -dX * s1 + dY * c1;
            msk[20 + k] = (fabsf(lX) <= hw1) & (fabsf(lY) <= hh1);
        }

        // centroid of valid points (divisor max(num,1), as reference)
        int num = 0;
        float cx = 0.0f, cy = 0.0f;
#pragma unroll
        for (int j = 0; j < 24; ++j) {
            num += msk[j] ? 1 : 0;
            cx += msk[j] ? ptx[j] : 0.0f;
            cy += msk[j] ? pty[j] : 0.0f;
        }
        float invnum = 1.0f / (float)(num > 1 ? num : 1);
        cx *= invnum;
        cy *= invnum;

#pragma unroll
        for (int j = 0; j < 24; ++j)
            ang[j] = msk[j] ? pseudo_angle(ptx[j] - cx, pty[j] - cy) : 1.0e8f;

        // Batcher odd-even mergesort network for n=32, comparators with
        // hi index >= 24 dropped (ascending-only => exact +inf padding).
        // All indices compile-time after full unroll => stays in VGPRs.
#pragma unroll
        for (int p = 1; p < 32; p <<= 1) {
#pragma unroll
            for (int k = p; k >= 1; k >>= 1) {
#pragma unroll
                for (int j = k % p; j + k < 32; j += 2 * k) {
#pragma unroll
                    for (int q = 0; q < k; ++q) {
                        int lo = q + j, hi = q + j + k;
                        if (hi < 24 && (lo / (2 * p)) == (hi / (2 * p))) {
                            float ka = ang[lo], kb = ang[hi];
                            bool sw = ka > kb;
                            ang[lo] = sw ? kb : ka;
                            ang[hi] = sw ? ka : kb;
                            float xa = ptx[lo], xb = ptx[hi];
                            ptx[lo] = sw ? xb : xa;
                            ptx[hi] = sw ? xa : xb;
                            float ya = pty[lo], yb = pty[hi];
                            pty[lo] = sw ? yb : ya;
                            pty[hi] = sw ? ya : yb;
                        }
                    }
                }
            }
        }

        // invalid points -> first sorted point (duplicates contribute 0)
        float fx = ptx[0], fy = pty[0];
#pragma unroll
        for (int j = 0; j < 24; ++j) {
            bool v = ang[j] < 1.0e7f;
            ptx[j] = v ? ptx[j] : fx;
            pty[j] = v ? pty[j] : fy;
        }

        // shoelace
        float acc = 0.0f;
#pragma unroll
        for (int j = 0; j < 24; ++j) {
            int jn = (j + 1) % 24;
            acc += ptx[j] * pty[jn] - pty[j] * ptx[jn];
        }
        float area = 0.5f * fabsf(acc);
        if (num < 3) area = 0.0f;

        float A1 = w1 * h1, A2 = w2 * h2;
        float iou = area / fmaxf(A1 + A2 - area, DEN_EPS_F);
        loss = -logf(fmaxf(iou, 1e-6f));
    }

    // wave (64-lane) reduction, then block, then one atomic per block
#pragma unroll
    for (int off = 32; off > 0; off >>= 1)
        loss += __shfl_down(loss, off, 64);

    __shared__ float wsum[4];
    int lane = threadIdx.x & 63;
    int wid = threadIdx.x >> 6;
    if (lane == 0) wsum[wid] = loss;
    __syncthreads();
    if (threadIdx.x == 0) {
        float s = (wsum[0] + wsum[1]) + (wsum[2] + wsum[3]);
        atomicAdd(out, s * inv_n);
    }
}

extern "C" void kernel_launch(void* const* d_in, const int* in_sizes, int n_in,
                              void* d_out, int out_size, void* d_ws, size_t ws_size,
                              hipStream_t stream) {
    const float* pred = (const float*)d_in[0];
    const float* target = (const float*)d_in[1];
    float* out = (float*)d_out;
    int n = in_sizes[0] / 5;

    // d_out is re-poisoned (0xAA) before every timed replay; zero it.
    hipMemsetAsync(out, 0, sizeof(float), stream);

    int block = 256;
    int grid = (n + block - 1) / block;
    riou_loss_kernel<<<grid, block, 0, stream>>>(pred, target, out, n,
                                                 1.0f / (float)n);
}

// Round 2
// 92.862 us; speedup vs baseline: 1.1259x; 1.1259x over previous
//
#include <hip/hip_runtime.h>
#include <math.h>

#define DEN_EPS_F 1e-10f

// Clip constraint |p + t*d| <= h onto the running interval [t0, t1].
// Branchless; handles the parallel (d ~ 0) case exactly.
__device__ __forceinline__ void axclip(float p, float d, float h,
                                       float& t0, float& t1) {
    float rd = 1.0f / d;
    float ta = (-h - p) * rd;
    float tb = ( h - p) * rd;
    float lo = fminf(ta, tb);
    float hi = fmaxf(ta, tb);
    bool par = fabsf(d) < 1e-12f;
    bool inside = fabsf(p) <= h;
    lo = par ? (inside ? -3.0e38f : 3.0e38f) : lo;
    hi = par ? (inside ?  3.0e38f : -3.0e38f) : hi;
    t0 = fmaxf(t0, lo);
    t1 = fminf(t1, hi);
}

__global__ __launch_bounds__(256) void riou_loss_kernel(
        const float* __restrict__ pred, const float* __restrict__ target,
        float* __restrict__ out, int n, float inv_n) {
    int i = blockIdx.x * blockDim.x + threadIdx.x;
    float loss = 0.0f;
    if (i < n) {
        const float* pb = pred + (size_t)i * 5;
        const float* tb = target + (size_t)i * 5;
        float x1 = pb[0], y1 = pb[1], w1 = pb[2], h1 = pb[3], a1 = pb[4];
        float x2 = tb[0], y2 = tb[1], w2 = tb[2], h2 = tb[3], a2 = tb[4];
        float s1, c1, s2, c2;
        sincosf(a1, &s1, &c1);
        sincosf(a2, &s2, &c2);

        float hw1 = 0.5f * w1, hh1 = 0.5f * h1;
        float hw2 = 0.5f * w2, hh2 = 0.5f * h2;

        // Global-frame corners, CCW. KX = {-1,1,1,-1}/2, KY = {-1,-1,1,1}/2.
        const float KX[4] = {-1.0f, 1.0f, 1.0f, -1.0f};
        const float KY[4] = {-1.0f, -1.0f, 1.0f, 1.0f};
        float px[4], py[4], qx[4], qy[4];
#pragma unroll
        for (int k = 0; k < 4; ++k) {
            float dx = KX[k] * hw1, dy = KY[k] * hh1;
            px[k] = x1 + dx * c1 - dy * s1;
            py[k] = y1 + dx * s1 + dy * c1;
            float ex = KX[k] * hw2, ey = KY[k] * hh2;
            qx[k] = x2 + ex * c2 - ey * s2;
            qy[k] = y2 + ex * s2 + ey * c2;
        }

        // Subject corners in the OTHER box's local frame (rotation by -a):
        // lx = dx*c + dy*s ; ly = -dx*s + dy*c
        float plx[4], ply[4], qlx[4], qly[4];
#pragma unroll
        for (int k = 0; k < 4; ++k) {
            float dx = px[k] - x2, dy = py[k] - y2;
            plx[k] = dx * c2 + dy * s2;
            ply[k] = -dx * s2 + dy * c2;
            float ex = qx[k] - x1, ey = qy[k] - y1;
            qlx[k] = ex * c1 + ey * s1;
            qly[k] = -ex * s1 + ey * c1;
        }

        // Boundary integral: sum of cross(A,B) over directed boundary
        // segments of the intersection (order-independent).
        float acc = 0.0f;

        // P edges clipped against Q's AABB (in Q local frame)
#pragma unroll
        for (int k = 0; k < 4; ++k) {
            int k1 = (k + 1) & 3;
            float dxl = plx[k1] - plx[k], dyl = ply[k1] - ply[k];
            float t0 = 0.0f, t1 = 1.0f;
            axclip(plx[k], dxl, hw2, t0, t1);
            axclip(ply[k], dyl, hh2, t0, t1);
            bool valid = t1 > t0;
            float rx = px[k1] - px[k], ry = py[k1] - py[k];
            float Ax = fmaf(t0, rx, px[k]), Ay = fmaf(t0, ry, py[k]);
            float Bx = fmaf(t1, rx, px[k]), By = fmaf(t1, ry, py[k]);
            float cr = Ax * By - Ay * Bx;
            acc += valid ? cr : 0.0f;
        }

        // Q edges clipped against P's AABB (in P local frame)
#pragma unroll
        for (int k = 0; k < 4; ++k) {
            int k1 = (k + 1) & 3;
            float dxl = qlx[k1] - qlx[k], dyl = qly[k1] - qly[k];
            float t0 = 0.0f, t1 = 1.0f;
            axclip(qlx[k], dxl, hw1, t0, t1);
            axclip(qly[k], dyl, hh1, t0, t1);
            bool valid = t1 > t0;
            float rx = qx[k1] - qx[k], ry = qy[k1] - qy[k];
            float Ax = fmaf(t0, rx, qx[k]), Ay = fmaf(t0, ry, qy[k]);
            float Bx = fmaf(t1, rx, qx[k]), By = fmaf(t1, ry, qy[k]);
            float cr = Ax * By - Ay * Bx;
            acc += valid ? cr : 0.0f;
        }

        float area = 0.5f * fabsf(acc);
        float A1 = w1 * h1, A2 = w2 * h2;
        float iou = area / fmaxf(A1 + A2 - area, DEN_EPS_F);
        loss = -logf(fmaxf(iou, 1e-6f));
    }

    // wave (64-lane) reduction, then block, then one atomic per block
#pragma unroll
    for (int off = 32; off > 0; off >>= 1)
        loss += __shfl_down(loss, off, 64);

    __shared__ float wsum[4];
    int lane = threadIdx.x & 63;
    int wid = threadIdx.x >> 6;
    if (lane == 0) wsum[wid] = loss;
    __syncthreads();
    if (threadIdx.x == 0) {
        float s = (wsum[0] + wsum[1]) + (wsum[2] + wsum[3]);
        atomicAdd(out, s * inv_n);
    }
}

extern "C" void kernel_launch(void* const* d_in, const int* in_sizes, int n_in,
                              void* d_out, int out_size, void* d_ws, size_t ws_size,
                              hipStream_t stream) {
    const float* pred = (const float*)d_in[0];
    const float* target = (const float*)d_in[1];
    float* out = (float*)d_out;
    int n = in_sizes[0] / 5;

    // d_out is re-poisoned (0xAA) before every timed replay; zero it.
    hipMemsetAsync(out, 0, sizeof(float), stream);

    int block = 256;
    int grid = (n + block - 1) / block;
    riou_loss_kernel<<<grid, block, 0, stream>>>(pred, target, out, n,
                                                 1.0f / (float)n);
}

// Round 3
// 92.053 us; speedup vs baseline: 1.1358x; 1.0088x over previous
//
#include <hip/hip_runtime.h>
#include <math.h>

#define DEN_EPS_F 1e-10f

// Clip constraint |p + t*d| <= h onto running interval [t0, t1].
// Branchless; parallel (d ~ 0) case overrides any NaN/Inf from rcp.
__device__ __forceinline__ void axclip(float p, float d, float h,
                                       float& t0, float& t1) {
    float rd = __builtin_amdgcn_rcpf(d);   // v_rcp_f32, ~1ulp
    float ta = (-h - p) * rd;
    float tb = ( h - p) * rd;
    float lo = fminf(ta, tb);
    float hi = fmaxf(ta, tb);
    bool par = fabsf(d) < 1e-12f;
    bool inside = fabsf(p) <= h;
    lo = par ? (inside ? -3.0e38f : 3.0e38f) : lo;
    hi = par ? (inside ?  3.0e38f : -3.0e38f) : hi;
    t0 = fmaxf(t0, lo);
    t1 = fminf(t1, hi);
}

__global__ __launch_bounds__(256) void riou_loss_kernel(
        const float* __restrict__ pred, const float* __restrict__ target,
        float* __restrict__ out, int n, float inv_n) {
    int i = blockIdx.x * blockDim.x + threadIdx.x;
    float loss = 0.0f;
    if (i < n) {
        const float* pb = pred + (size_t)i * 5;
        const float* tb = target + (size_t)i * 5;
        float x1 = pb[0], y1 = pb[1], w1 = pb[2], h1 = pb[3], a1 = pb[4];
        float x2 = tb[0], y2 = tb[1], w2 = tb[2], h2 = tb[3], a2 = tb[4];
        float s1, c1, s2, c2;
        __sincosf(a1, &s1, &c1);   // v_sin_f32 / v_cos_f32
        __sincosf(a2, &s2, &c2);

        float hw1 = 0.5f * w1, hh1 = 0.5f * h1;
        float hw2 = 0.5f * w2, hh2 = 0.5f * h2;

        // Work in frame translated by (x1,y1): keeps cross products ~1e4.
        float tx = x2 - x1, ty = y2 - y1;

        // Half-edge vectors u (width dir), v (height dir), both boxes.
        float ux1 = hw1 * c1, uy1 = hw1 * s1;
        float vx1 = -hh1 * s1, vy1 = hh1 * c1;
        float ux2 = hw2 * c2, uy2 = hw2 * s2;
        float vx2 = -hh2 * s2, vy2 = hh2 * c2;

        // Corners CCW: (-u-v), (u-v), (u+v), (-u+v)  [+ center]
        float px[4], py[4], qx[4], qy[4];
        px[0] = -ux1 - vx1; py[0] = -uy1 - vy1;
        px[1] =  ux1 - vx1; py[1] =  uy1 - vy1;
        px[2] =  ux1 + vx1; py[2] =  uy1 + vy1;
        px[3] = -ux1 + vx1; py[3] = -uy1 + vy1;
        qx[0] = tx - ux2 - vx2; qy[0] = ty - uy2 - vy2;
        qx[1] = tx + ux2 - vx2; qy[1] = ty + uy2 - vy2;
        qx[2] = tx + ux2 + vx2; qy[2] = ty + uy2 + vy2;
        qx[3] = tx - ux2 + vx2; qy[3] = ty - uy2 + vy2;

        // Subject corners in the OTHER box's local frame (rotate by -a).
        float plx[4], ply[4], qlx[4], qly[4];
#pragma unroll
        for (int k = 0; k < 4; ++k) {
            float dx = px[k] - tx, dy = py[k] - ty;
            plx[k] = dx * c2 + dy * s2;
            ply[k] = -dx * s2 + dy * c2;
            float ex = qx[k], ey = qy[k];
            qlx[k] = ex * c1 + ey * s1;
            qly[k] = -ex * s1 + ey * c1;
        }

        // Order-independent boundary integral of the intersection:
        // P edges clipped to Q's local AABB + Q edges clipped to P's.
        float acc = 0.0f;
#pragma unroll
        for (int k = 0; k < 4; ++k) {
            int k1 = (k + 1) & 3;
            float dxl = plx[k1] - plx[k], dyl = ply[k1] - ply[k];
            float t0 = 0.0f, t1 = 1.0f;
            axclip(plx[k], dxl, hw2, t0, t1);
            axclip(ply[k], dyl, hh2, t0, t1);
            bool valid = t1 > t0;
            float rx = px[k1] - px[k], ry = py[k1] - py[k];
            float Ax = fmaf(t0, rx, px[k]), Ay = fmaf(t0, ry, py[k]);
            float Bx = fmaf(t1, rx, px[k]), By = fmaf(t1, ry, py[k]);
            float cr = Ax * By - Ay * Bx;
            acc += valid ? cr : 0.0f;
        }
#pragma unroll
        for (int k = 0; k < 4; ++k) {
            int k1 = (k + 1) & 3;
            float dxl = qlx[k1] - qlx[k], dyl = qly[k1] - qly[k];
            float t0 = 0.0f, t1 = 1.0f;
            axclip(qlx[k], dxl, hw1, t0, t1);
            axclip(qly[k], dyl, hh1, t0, t1);
            bool valid = t1 > t0;
            float rx = qx[k1] - qx[k], ry = qy[k1] - qy[k];
            float Ax = fmaf(t0, rx, qx[k]), Ay = fmaf(t0, ry, qy[k]);
            float Bx = fmaf(t1, rx, qx[k]), By = fmaf(t1, ry, qy[k]);
            float cr = Ax * By - Ay * Bx;
            acc += valid ? cr : 0.0f;
        }

        float area = 0.5f * fabsf(acc);
        float A1 = w1 * h1, A2 = w2 * h2;
        float iou = __fdividef(area, fmaxf(A1 + A2 - area, DEN_EPS_F));
        loss = -__logf(fmaxf(iou, 1e-6f));
    }

    // wave (64-lane) reduction -> LDS across 4 waves -> 1 atomic/block
#pragma unroll
    for (int off = 32; off > 0; off >>= 1)
        loss += __shfl_down(loss, off, 64);

    __shared__ float wsum[4];
    int lane = threadIdx.x & 63;
    int wid = threadIdx.x >> 6;
    if (lane == 0) wsum[wid] = loss;
    __syncthreads();
    if (threadIdx.x == 0) {
        float s = (wsum[0] + wsum[1]) + (wsum[2] + wsum[3]);
        atomicAdd(out, s * inv_n);
    }
}

extern "C" void kernel_launch(void* const* d_in, const int* in_sizes, int n_in,
                              void* d_out, int out_size, void* d_ws, size_t ws_size,
                              hipStream_t stream) {
    const float* pred = (const float*)d_in[0];
    const float* target = (const float*)d_in[1];
    float* out = (float*)d_out;
    int n = in_sizes[0] / 5;

    // d_out is re-poisoned (0xAA) before every timed replay; zero it.
    hipMemsetAsync(out, 0, sizeof(float), stream);

    int block = 256;
    int grid = (n + block - 1) / block;
    riou_loss_kernel<<<grid, block, 0, stream>>>(pred, target, out, n,
                                                 1.0f / (float)n);
}

// Round 4
// 75.984 us; speedup vs baseline: 1.3760x; 1.2115x over previous
//
#include <hip/hip_runtime.h>
#include <math.h>

#define DEN_EPS_F 1e-10f

// Clip |p + t*d| <= h onto running interval [t0, t1].
// Near-parallel d is clamped to a tiny slope: |t| ~ 1e13 lands far outside
// [0,1], which reproduces exact inside/outside/empty behavior with no
// NaN/Inf special cases.
__device__ __forceinline__ void axclip(float p, float d, float h,
                                       float& t0, float& t1) {
    float dc = (fabsf(d) < 1e-12f) ? 1e-12f : d;
    float rd = __builtin_amdgcn_rcpf(dc);   // v_rcp_f32
    float ta = (-h - p) * rd;
    float tb = ( h - p) * rd;
    t0 = fmaxf(t0, fminf(ta, tb));
    t1 = fminf(t1, fmaxf(ta, tb));
}

// Loss for one (pred, target) pair; bp/bt point at 5 floats each.
// All indexing compile-time -> fully register-resident after inlining.
__device__ __forceinline__ float box_pair_loss(const float* bp, const float* bt) {
    float x1 = bp[0], y1 = bp[1], w1 = bp[2], h1 = bp[3], a1 = bp[4];
    float x2 = bt[0], y2 = bt[1], w2 = bt[2], h2 = bt[3], a2 = bt[4];
    float s1, c1, s2, c2;
    __sincosf(a1, &s1, &c1);   // v_sin_f32 / v_cos_f32
    __sincosf(a2, &s2, &c2);

    float hw1 = 0.5f * w1, hh1 = 0.5f * h1;
    float hw2 = 0.5f * w2, hh2 = 0.5f * h2;

    // Frame translated by (x1,y1): keeps cross-product magnitudes ~1e4.
    float tx = x2 - x1, ty = y2 - y1;

    float ux1 = hw1 * c1, uy1 = hw1 * s1;
    float vx1 = -hh1 * s1, vy1 = hh1 * c1;
    float ux2 = hw2 * c2, uy2 = hw2 * s2;
    float vx2 = -hh2 * s2, vy2 = hh2 * c2;

    // Corners CCW: (-u-v), (u-v), (u+v), (-u+v)
    float px[4], py[4], qx[4], qy[4];
    px[0] = -ux1 - vx1; py[0] = -uy1 - vy1;
    px[1] =  ux1 - vx1; py[1] =  uy1 - vy1;
    px[2] =  ux1 + vx1; py[2] =  uy1 + vy1;
    px[3] = -ux1 + vx1; py[3] = -uy1 + vy1;
    qx[0] = tx - ux2 - vx2; qy[0] = ty - uy2 - vy2;
    qx[1] = tx + ux2 - vx2; qy[1] = ty + uy2 - vy2;
    qx[2] = tx + ux2 + vx2; qy[2] = ty + uy2 + vy2;
    qx[3] = tx - ux2 + vx2; qy[3] = ty - uy2 + vy2;

    // Subject corners in the OTHER box's local frame (rotate by -a).
    float plx[4], ply[4], qlx[4], qly[4];
#pragma unroll
    for (int k = 0; k < 4; ++k) {
        float dx = px[k] - tx, dy = py[k] - ty;
        plx[k] = dx * c2 + dy * s2;
        ply[k] = -dx * s2 + dy * c2;
        float ex = qx[k], ey = qy[k];
        qlx[k] = ex * c1 + ey * s1;
        qly[k] = -ex * s1 + ey * c1;
    }

    // Order-independent boundary integral of the intersection:
    // {P edges clipped to Q's local AABB} + {Q edges clipped to P's}.
    float acc = 0.0f;
#pragma unroll
    for (int k = 0; k < 4; ++k) {
        int k1 = (k + 1) & 3;
        float dxl = plx[k1] - plx[k], dyl = ply[k1] - ply[k];
        float t0 = 0.0f, t1 = 1.0f;
        axclip(plx[k], dxl, hw2, t0, t1);
        axclip(ply[k], dyl, hh2, t0, t1);
        bool valid = t1 > t0;
        float rx = px[k1] - px[k], ry = py[k1] - py[k];
        float Ax = fmaf(t0, rx, px[k]), Ay = fmaf(t0, ry, py[k]);
        float Bx = fmaf(t1, rx, px[k]), By = fmaf(t1, ry, py[k]);
        float cr = Ax * By - Ay * Bx;
        acc += valid ? cr : 0.0f;
    }
#pragma unroll
    for (int k = 0; k < 4; ++k) {
        int k1 = (k + 1) & 3;
        float dxl = qlx[k1] - qlx[k], dyl = qly[k1] - qly[k];
        float t0 = 0.0f, t1 = 1.0f;
        axclip(qlx[k], dxl, hw1, t0, t1);
        axclip(qly[k], dyl, hh1, t0, t1);
        bool valid = t1 > t0;
        float rx = qx[k1] - qx[k], ry = qy[k1] - qy[k];
        float Ax = fmaf(t0, rx, qx[k]), Ay = fmaf(t0, ry, qy[k]);
        float Bx = fmaf(t1, rx, qx[k]), By = fmaf(t1, ry, qy[k]);
        float cr = Ax * By - Ay * Bx;
        acc += valid ? cr : 0.0f;
    }

    float area = 0.5f * fabsf(acc);
    float uni = fmaxf(fmaf(w1, h1, w2 * h2) - area, DEN_EPS_F);
    float iou = area * __builtin_amdgcn_rcpf(uni);
    return -__logf(fmaxf(iou, 1e-6f));
}

#define BOX_PER_THREAD 4

__global__ __launch_bounds__(256, 2) void riou_loss_kernel(
        const float* __restrict__ pred, const float* __restrict__ target,
        float* __restrict__ out, int n, float inv_n) {
    int t = blockIdx.x * blockDim.x + threadIdx.x;
    int base = t * BOX_PER_THREAD;
    float loss = 0.0f;

    if (base + BOX_PER_THREAD - 1 < n) {
        // 4 boxes x 5 floats = 5 x float4, byte offset t*80 (16B aligned).
        const float4* p4 = reinterpret_cast<const float4*>(pred) + (size_t)t * 5;
        const float4* t4 = reinterpret_cast<const float4*>(target) + (size_t)t * 5;
        float fp[20], ft[20];
#pragma unroll
        for (int k = 0; k < 5; ++k) {
            float4 v = p4[k];
            fp[4 * k + 0] = v.x; fp[4 * k + 1] = v.y;
            fp[4 * k + 2] = v.z; fp[4 * k + 3] = v.w;
            float4 u = t4[k];
            ft[4 * k + 0] = u.x; ft[4 * k + 1] = u.y;
            ft[4 * k + 2] = u.z; ft[4 * k + 3] = u.w;
        }
#pragma unroll
        for (int b = 0; b < BOX_PER_THREAD; ++b)
            loss += box_pair_loss(fp + 5 * b, ft + 5 * b);
    } else if (base < n) {
        // ragged tail (never taken when n % 4 == 0): scalar loads from global
        for (int b = 0; b < BOX_PER_THREAD; ++b) {
            int idx = base + b;
            if (idx < n)
                loss += box_pair_loss(pred + (size_t)idx * 5,
                                      target + (size_t)idx * 5);
        }
    }

    // wave (64-lane) reduction -> LDS across 4 waves -> 1 atomic/block
#pragma unroll
    for (int off = 32; off > 0; off >>= 1)
        loss += __shfl_down(loss, off, 64);

    __shared__ float wsum[4];
    int lane = threadIdx.x & 63;
    int wid = threadIdx.x >> 6;
    if (lane == 0) wsum[wid] = loss;
    __syncthreads();
    if (threadIdx.x == 0) {
        float s = (wsum[0] + wsum[1]) + (wsum[2] + wsum[3]);
        atomicAdd(out, s * inv_n);
    }
}

extern "C" void kernel_launch(void* const* d_in, const int* in_sizes, int n_in,
                              void* d_out, int out_size, void* d_ws, size_t ws_size,
                              hipStream_t stream) {
    const float* pred = (const float*)d_in[0];
    const float* target = (const float*)d_in[1];
    float* out = (float*)d_out;
    int n = in_sizes[0] / 5;

    // d_out is re-poisoned (0xAA) before every timed replay; zero it.
    hipMemsetAsync(out, 0, sizeof(float), stream);

    int threads_needed = (n + BOX_PER_THREAD - 1) / BOX_PER_THREAD;
    int block = 256;
    int grid = (threads_needed + block - 1) / block;
    riou_loss_kernel<<<grid, block, 0, stream>>>(pred, target, out, n,
                                                 1.0f / (float)n);
}